// Round 7
// baseline (191.632 us; speedup 1.0000x reference)
//
#include <hip/hip_runtime.h>
#include <math.h>

#define N 4096
#define B 16
#define NN (N * N)
#define R 4                    // rows per block (fallback fused kernel)
#define MAX_SYN 100
#define MIN_SYN 10
#define CREATE_T 0.3f
#define PRUNE_T 0.01f
#define INIT_STRENGTH 0.01f
#define EPS 1e-10f
#define BF_BASE 0x3E9Au        // bf16 code of smallest candidate magnitude (>0.3 RNE-rounds to >= 0x3E9A)
#define WEAK 0x7Fu             // enc code: weak existing synapse (EPS<|w|<PRUNE_T); cand codes are 1..126|sign
#define CAPM 96                // boundary (tie) list cap per row
#define CAPS 32                // small-weight list cap (fallback kernel only)
#define NSLOT 64

typedef float f32x4 __attribute__((ext_vector_type(4)));
typedef unsigned u32x4 __attribute__((ext_vector_type(4)));

// ---------------- kernel 1: per-column normalization + acc zeroing ----------------
__global__ void prep_kernel(const float* __restrict__ act,
                            float* __restrict__ norm,
                            float* __restrict__ acc) {
    int j = blockIdx.x * blockDim.x + threadIdx.x;
    if (blockIdx.x == 0 && threadIdx.x < NSLOT * 4) acc[threadIdx.x] = 0.f;
    if (j >= N) return;
    float a[B];
    float sum = 0.f;
#pragma unroll
    for (int b = 0; b < B; ++b) { a[b] = act[b * N + j]; sum += a[b]; }
    float mean = sum * (1.0f / B);
    float var = 0.f;
#pragma unroll
    for (int b = 0; b < B; ++b) { float c = a[b] - mean; var += c * c; }
    var *= (1.0f / (B - 1));   // ddof=1
    float sd = sqrtf(var);
    if (sd < 1e-8f) sd = 1e-8f;
    float inv = 1.0f / sd;
#pragma unroll
    for (int b = 0; b < B; ++b) norm[b * N + j] = (a[b] - mean) * inv;
}

// ---------------- kernel 2a: pure stream — corr + copy + u8 encode + counts ----------------
// NO LDS, NO barriers, NO hot-loop atomics. Block = 4 rows x 2048-col half, 256 threads.
// Grid 2048 -> 8 blocks/CU if VGPR<=64 (R5 codegen: exactly 64 for this body).
// enc code per element: 0 = nothing; WEAK(0x7F) = weak existing synapse;
// else bit7 = sign(corr), bits0..6 = bin+1, bin = (bf16(|corr|) - BF_BASE) >> 1.
// Count partials go to per-(row,wave)-slot global ints (plain stores, no init needed).
__global__ __launch_bounds__(256, 4) void stream_kernel(const float* __restrict__ W,
                                                        const float* __restrict__ norm,
                                                        float* __restrict__ out,
                                                        unsigned char* __restrict__ enc,
                                                        int* __restrict__ rowcnt) {
    const int tid = threadIdx.x;
    const int lane = tid & 63;
    const int wid = tid >> 6;               // 0..3
    const int half = blockIdx.x & 1;        // column half
    const int row0 = (blockIdx.x >> 1) * 4;
    const int cbase = half * 2048;

    // wave-uniform row vectors -> scalar loads
    float srow[4][B];
#pragma unroll
    for (int r = 0; r < 4; ++r)
#pragma unroll
        for (int b = 0; b < B; ++b) srow[r][b] = norm[b * N + row0 + r];

    int cnt_nz[4], cnt_cand[4], cnt_str[4];
#pragma unroll
    for (int r = 0; r < 4; ++r) { cnt_nz[r] = 0; cnt_cand[r] = 0; cnt_str[r] = 0; }

#pragma unroll
    for (int g = 0; g < 2; ++g) {
        const int j0 = cbase + g * 1024 + tid * 4;
        f32x4 w4[4];
#pragma unroll
        for (int r = 0; r < 4; ++r)
            w4[r] = __builtin_nontemporal_load((const f32x4*)(W + (size_t)(row0 + r) * N + j0));

        float cc[4][4];
#pragma unroll
        for (int r = 0; r < 4; ++r) { cc[r][0] = 0.f; cc[r][1] = 0.f; cc[r][2] = 0.f; cc[r][3] = 0.f; }
#pragma unroll
        for (int bh = 0; bh < 2; ++bh) {
            f32x4 nb[8];
#pragma unroll
            for (int b = 0; b < 8; ++b)
                nb[b] = *(const f32x4*)(norm + (bh * 8 + b) * N + j0);
#pragma unroll
            for (int r = 0; r < 4; ++r) {
#pragma unroll
                for (int b = 0; b < 8; ++b) {
                    float s = srow[r][bh * 8 + b];
                    cc[r][0] = fmaf(s, nb[b][0], cc[r][0]);
                    cc[r][1] = fmaf(s, nb[b][1], cc[r][1]);
                    cc[r][2] = fmaf(s, nb[b][2], cc[r][2]);
                    cc[r][3] = fmaf(s, nb[b][3], cc[r][3]);
                }
            }
        }

        // streaming copy W -> out (fix-ups land in kernel 2b, next dispatch)
#pragma unroll
        for (int r = 0; r < 4; ++r)
            __builtin_nontemporal_store(w4[r], (f32x4*)(out + (size_t)(row0 + r) * N + j0));

        // encode 4 codes per row into one u32, plain store (L2/L3 for 2b to read)
#pragma unroll
        for (int r = 0; r < 4; ++r) {
            unsigned pack = 0;
#pragma unroll
            for (int i = 0; i < 4; ++i) {
                float c = cc[r][i] * 0.0625f;       // /16
                float aw = fabsf(w4[r][i]);
                float ac = fabsf(c);
                int isnz = (aw > EPS) ? 1 : 0;
                int cand = ((ac > CREATE_T) && (aw < EPS)) ? 1 : 0;
                cnt_nz[r] += isnz;
                cnt_cand[r] += cand;
                cnt_str[r] += (aw >= PRUNE_T) ? 1 : 0;
                unsigned bits = __float_as_uint(ac);
                unsigned mag = (bits + 0x7FFFu + ((bits >> 16) & 1u)) >> 16;  // RNE bf16
                unsigned bin = (mag - BF_BASE) >> 1;
                if (bin > 125u) bin = 125u;          // safety; real max 107
                unsigned e = cand ? ((bin + 1u) | ((c < 0.f) ? 0x80u : 0u)) : 0u;
                if (isnz && aw < PRUNE_T) e = WEAK;  // weak existing synapse marker
                pack |= e << (8 * i);
            }
            *(unsigned*)(enc + (size_t)(row0 + r) * N + j0) = pack;
        }
    }

    // wave-reduce 8 packed counters, lane 0 stores to per-(row, slot) global ints
    int outv[8];
#pragma unroll
    for (int r = 0; r < 4; ++r) {
        outv[r] = cnt_nz[r] | (cnt_str[r] << 16);
        outv[4 + r] = cnt_cand[r];
    }
#pragma unroll
    for (int v = 0; v < 8; ++v) {
        int x = outv[v];
#pragma unroll
        for (int off = 32; off > 0; off >>= 1) x += __shfl_down(x, off, 64);
        outv[v] = x;
    }
    if (lane == 0) {
        const int slot = half * 4 + wid;    // 0..7
#pragma unroll
        for (int r = 0; r < 4; ++r) {
            const int base = ((row0 + r) * 8 + slot) * 2;
            rowcnt[base] = outv[r];
            rowcnt[base + 1] = outv[4 + r];
        }
    }
}

// ---------------- kernel 2b: one wave per row — selection + fix-ups + stats ----------------
// Grid 4096 x 64 threads. All LDS wave-private; zero barriers (within-wave DS ordering).
__global__ __launch_bounds__(64) void select_kernel(const unsigned char* __restrict__ enc,
                                                    const int* __restrict__ rowcnt,
                                                    float* __restrict__ out,
                                                    float* __restrict__ acc) {
    __shared__ int hist[128];
    __shared__ unsigned mlist[CAPM];
    __shared__ int mcnt;

    const int lane = threadIdx.x;
    const int row = blockIdx.x;
    const size_t rowoff = (size_t)row * N;

    // sum the 8 count slots
    int t = 0, C = 0;
#pragma unroll
    for (int s = 0; s < 8; ++s) {
        t += rowcnt[(row * 8 + s) * 2];
        C += rowcnt[(row * 8 + s) * 2 + 1];
    }
    const int nz = t & 0xFFFF;
    const int str = t >> 16;
    int nw = 0;
    if (nz < MAX_SYN) { int room = MAX_SYN - nz; nw = C < room ? C : room; }
    const int cpw = ((str + nw) > MIN_SYN) ? 1 : 0;

    if (lane == 0) {
        mcnt = 0;
        int strong = str + nw;
        float* slot = acc + (row & (NSLOT - 1)) * 4;
        atomicAdd(slot + 0, (float)nw);
        atomicAdd(slot + 1, (float)(cpw ? (N - strong) : 0));
        atomicAdd(slot + 2, (float)((N - nz - nw) + (cpw ? (nz - str) : 0)));
    }
    const bool selh = (nw > 0) && (nw < C);

    // load own row's 4096 codes: 4 x dwordx4 per lane (1 KB per wave per iter)
    u32x4 ev[4];
#pragma unroll
    for (int q = 0; q < 4; ++q)
        ev[q] = *(const u32x4*)(enc + rowoff + (size_t)(q * 64 + lane) * 16);

    // histogram (wave-private; DS ops from one wave execute in order)
    hist[lane] = 0;
    hist[64 + lane] = 0;
    if (selh) {
#pragma unroll
        for (int q = 0; q < 4; ++q)
#pragma unroll
            for (int d = 0; d < 4; ++d) {
                unsigned u = ev[q][d];
                if (!u) continue;
#pragma unroll
                for (int i = 0; i < 4; ++i) {
                    unsigned e = (u >> (8 * i)) & 0xFFu;
                    if (e && e != WEAK) atomicAdd(&hist[(e & 0x7Fu) - 1u], 1);
                }
            }
    }

    int cutbin = (nw > 0) ? -1 : 0x7FFFFFFF;
    int mm = 0;
    if (selh) {
        int h[2], v[2];
#pragma unroll
        for (int q = 0; q < 2; ++q) { h[q] = hist[q * 64 + lane]; v[q] = h[q]; }
#pragma unroll
        for (int off = 1; off < 64; off <<= 1) {
#pragma unroll
            for (int q = 0; q < 2; ++q) {
                int tt = __shfl_down(v[q], off, 64);
                v[q] += (lane + off < 64) ? tt : 0;
            }
        }
        int T1 = __shfl(v[1], 0, 64);           // total of bins 64..127
        int cb = 128;
#pragma unroll
        for (int q = 0; q < 2; ++q) {
            int S = v[q] + (q == 0 ? T1 : 0);   // # entries with bin >= q*64+lane
            if (S >= nw && S - h[q] < nw) { cb = q * 64 + lane; mm = nw - (S - h[q]); }
        }
#pragma unroll
        for (int off = 1; off < 64; off <<= 1) {
            int cb2 = __shfl_xor(cb, off, 64);
            int mm2 = __shfl_xor(mm, off, 64);
            cb = cb < cb2 ? cb : cb2;
            mm = mm > mm2 ? mm : mm2;
        }
        cutbin = cb;
    }

    // classify: creates above cut, boundary ties to mlist, weak prunes inline
    if (nw > 0 || cpw) {
#pragma unroll
        for (int q = 0; q < 4; ++q)
#pragma unroll
            for (int d = 0; d < 4; ++d) {
                unsigned u = ev[q][d];
                if (!u) continue;
#pragma unroll
                for (int i = 0; i < 4; ++i) {
                    unsigned e = (u >> (8 * i)) & 0xFFu;
                    if (!e) continue;
                    const int col = q * 1024 + lane * 16 + d * 4 + i;
                    if (e == WEAK) {
                        if (cpw) out[rowoff + col] = 0.f;
                    } else if (nw > 0) {
                        int bin = (int)(e & 0x7Fu) - 1;
                        if (bin > cutbin) {
                            out[rowoff + col] = (e & 0x80u) ? -INIT_STRENGTH : INIT_STRENGTH;
                        } else if (bin == cutbin) {
                            int idx = atomicAdd(&mcnt, 1);
                            if (idx < CAPM) mlist[idx] = (e << 16) | (unsigned)col;
                        }
                    }
                }
            }
    }

    // ties: take mm smallest columns in the cut bin
    if (nw > 0) {
        int L = mcnt; if (L > CAPM) L = CAPM;
        for (int t0 = 0; t0 < L; t0 += 64) {
            int k = t0 + lane;
            if (k < L) {
                unsigned me = mlist[k];
                int mycol = (int)(me & 0xFFFFu);
                int rk = 0;
                for (int t2 = 0; t2 < L; ++t2)
                    rk += ((int)(mlist[t2] & 0xFFFFu) < mycol) ? 1 : 0;
                if (rk < mm)
                    out[rowoff + mycol] = (me & 0x800000u) ? -INIT_STRENGTH : INIT_STRENGTH;
            }
        }
    }
}

// ---------------- fallback fused kernel (round-5, proven): used if ws too small ----------------
__global__ __launch_bounds__(256, 4) void fused_kernel(const float* __restrict__ W,
                                                       const float* __restrict__ norm,
                                                       float* __restrict__ out,
                                                       float* __restrict__ acc) {
    __shared__ unsigned char enc[R][N];
    __shared__ int hist[R][128];
    __shared__ unsigned mlist[R][CAPM];
    __shared__ unsigned short slist[R][CAPS];
    __shared__ int scnt[R];
    __shared__ int mcnt[R];
    __shared__ int red[4][8];

    const int tid = threadIdx.x;
    const int lane = tid & 63;
    const int wid = tid >> 6;
    const int row0 = blockIdx.x * R;

    if (tid < R) { scnt[tid] = 0; mcnt[tid] = 0; }
#pragma unroll
    for (int q = 0; q < 2; ++q) ((int*)hist)[q * 256 + tid] = 0;

    float srow[R][B];
#pragma unroll
    for (int r = 0; r < R; ++r)
#pragma unroll
        for (int b = 0; b < B; ++b) srow[r][b] = norm[b * N + row0 + r];

    __syncthreads();

    int cnt_nz[R], cnt_cand[R], cnt_str[R];
#pragma unroll
    for (int r = 0; r < R; ++r) { cnt_nz[r] = 0; cnt_cand[r] = 0; cnt_str[r] = 0; }

#pragma unroll
    for (int g = 0; g < 4; ++g) {
        const int j0 = g * 1024 + tid * 4;
        f32x4 w4[R];
#pragma unroll
        for (int r = 0; r < R; ++r)
            w4[r] = __builtin_nontemporal_load((const f32x4*)(W + (size_t)(row0 + r) * N + j0));
        float cc[R][4];
#pragma unroll
        for (int r = 0; r < R; ++r) { cc[r][0] = 0.f; cc[r][1] = 0.f; cc[r][2] = 0.f; cc[r][3] = 0.f; }
#pragma unroll
        for (int bh = 0; bh < 2; ++bh) {
            f32x4 nb[8];
#pragma unroll
            for (int b = 0; b < 8; ++b)
                nb[b] = *(const f32x4*)(norm + (bh * 8 + b) * N + j0);
#pragma unroll
            for (int r = 0; r < R; ++r) {
#pragma unroll
                for (int b = 0; b < 8; ++b) {
                    float s = srow[r][bh * 8 + b];
                    cc[r][0] = fmaf(s, nb[b][0], cc[r][0]);
                    cc[r][1] = fmaf(s, nb[b][1], cc[r][1]);
                    cc[r][2] = fmaf(s, nb[b][2], cc[r][2]);
                    cc[r][3] = fmaf(s, nb[b][3], cc[r][3]);
                }
            }
        }
#pragma unroll
        for (int r = 0; r < R; ++r)
            __builtin_nontemporal_store(w4[r], (f32x4*)(out + (size_t)(row0 + r) * N + j0));
#pragma unroll
        for (int r = 0; r < R; ++r) {
            unsigned pack = 0;
#pragma unroll
            for (int i = 0; i < 4; ++i) {
                float c = cc[r][i] * 0.0625f;
                float aw = fabsf(w4[r][i]);
                float ac = fabsf(c);
                int isnz = (aw > EPS) ? 1 : 0;
                int cand = ((ac > CREATE_T) && (aw < EPS)) ? 1 : 0;
                cnt_nz[r] += isnz;
                cnt_cand[r] += cand;
                cnt_str[r] += (aw >= PRUNE_T) ? 1 : 0;
                if (isnz && aw < PRUNE_T) {
                    int idx = atomicAdd(&scnt[r], 1);
                    if (idx < CAPS) slist[r][idx] = (unsigned short)(j0 + i);
                }
                unsigned bits = __float_as_uint(ac);
                unsigned mag = (bits + 0x7FFFu + ((bits >> 16) & 1u)) >> 16;
                unsigned bin = (mag - BF_BASE) >> 1;
                if (bin > 125u) bin = 125u;
                unsigned e = cand ? ((bin + 1u) | ((c < 0.f) ? 0x80u : 0u)) : 0u;
                pack |= e << (8 * i);
            }
            *(unsigned*)&enc[r][j0] = pack;
        }
    }

    int vals[8];
#pragma unroll
    for (int r = 0; r < R; ++r) {
        vals[r] = cnt_nz[r] | (cnt_str[r] << 16);
        vals[4 + r] = cnt_cand[r];
    }
#pragma unroll
    for (int v = 0; v < 8; ++v) {
        int x = vals[v];
#pragma unroll
        for (int off = 32; off > 0; off >>= 1) x += __shfl_down(x, off, 64);
        if (lane == 0) red[wid][v] = x;
    }
    __syncthreads();

    if (tid == 0) {
        int created_total = 0, pruned_total = 0, zeros_total = 0;
#pragma unroll
        for (int r = 0; r < R; ++r) {
            int t = red[0][r] + red[1][r] + red[2][r] + red[3][r];
            int C = red[0][4 + r] + red[1][4 + r] + red[2][4 + r] + red[3][4 + r];
            int nz = t & 0xFFFF, str = t >> 16;
            int n = 0;
            if (nz < MAX_SYN) { int room = MAX_SYN - nz; n = C < room ? C : room; }
            int strong = str + n;
            int cp = (strong > MIN_SYN) ? 1 : 0;
            created_total += n;
            pruned_total += cp ? (N - strong) : 0;
            zeros_total += (N - nz - n) + (cp ? (nz - str) : 0);
        }
        float* slot = acc + (blockIdx.x & (NSLOT - 1)) * 4;
        atomicAdd(slot + 0, (float)created_total);
        atomicAdd(slot + 1, (float)pruned_total);
        atomicAdd(slot + 2, (float)zeros_total);
    }

    const int tw = red[0][wid] + red[1][wid] + red[2][wid] + red[3][wid];
    const int nzw = tw & 0xFFFF;
    const int strw = tw >> 16;
    const int Cw = red[0][4 + wid] + red[1][4 + wid] + red[2][4 + wid] + red[3][4 + wid];
    int nw = 0;
    if (nzw < MAX_SYN) { int room = MAX_SYN - nzw; nw = Cw < room ? Cw : room; }
    const int cpw = ((strw + nw) > MIN_SYN) ? 1 : 0;
    const size_t rowoff = (size_t)(row0 + wid) * N;
    const bool selh = (nw > 0) && (nw < Cw);

    if (selh) {
#pragma unroll
        for (int t = 0; t < 16; ++t) {
            unsigned ev = *(const unsigned*)&enc[wid][(t * 64 + lane) * 4];
            if (!ev) continue;
#pragma unroll
            for (int i = 0; i < 4; ++i) {
                unsigned e = (ev >> (8 * i)) & 0xFFu;
                if (e) atomicAdd(&hist[wid][(e & 0x7Fu) - 1u], 1);
            }
        }
    }

    int cutbin = (nw > 0) ? -1 : 0x7FFFFFFF;
    int mm = 0;
    if (selh) {
        int h[2], v[2];
#pragma unroll
        for (int q = 0; q < 2; ++q) { h[q] = hist[wid][q * 64 + lane]; v[q] = h[q]; }
#pragma unroll
        for (int off = 1; off < 64; off <<= 1) {
#pragma unroll
            for (int q = 0; q < 2; ++q) {
                int t = __shfl_down(v[q], off, 64);
                v[q] += (lane + off < 64) ? t : 0;
            }
        }
        int T1 = __shfl(v[1], 0, 64);
        int cb = 128;
#pragma unroll
        for (int q = 0; q < 2; ++q) {
            int S = v[q] + (q == 0 ? T1 : 0);
            if (S >= nw && S - h[q] < nw) { cb = q * 64 + lane; mm = nw - (S - h[q]); }
        }
#pragma unroll
        for (int off = 1; off < 64; off <<= 1) {
            int cb2 = __shfl_xor(cb, off, 64);
            int mm2 = __shfl_xor(mm, off, 64);
            cb = cb < cb2 ? cb : cb2;
            mm = mm > mm2 ? mm : mm2;
        }
        cutbin = cb;
    }

    if (nw > 0) {
#pragma unroll
        for (int t = 0; t < 16; ++t) {
            const int si = (t * 64 + lane) * 4;
            unsigned ev = *(const unsigned*)&enc[wid][si];
            if (!ev) continue;
#pragma unroll
            for (int i = 0; i < 4; ++i) {
                unsigned e = (ev >> (8 * i)) & 0xFFu;
                int bin = (int)(e & 0x7Fu) - 1;
                if (e && bin > cutbin) {
                    out[rowoff + si + i] = (e & 0x80u) ? -INIT_STRENGTH : INIT_STRENGTH;
                } else if (e && bin == cutbin) {
                    int idx = atomicAdd(&mcnt[wid], 1);
                    if (idx < CAPM) mlist[wid][idx] = (e << 16) | (unsigned)(si + i);
                }
            }
        }
        int L = mcnt[wid]; if (L > CAPM) L = CAPM;
        for (int t0 = 0; t0 < L; t0 += 64) {
            int t = t0 + lane;
            if (t < L) {
                unsigned me = mlist[wid][t];
                int mycol = (int)(me & 0xFFFFu);
                int rk = 0;
                for (int t2 = 0; t2 < L; ++t2)
                    rk += ((int)(mlist[wid][t2] & 0xFFFFu) < mycol) ? 1 : 0;
                if (rk < mm)
                    out[rowoff + mycol] = (me & 0x800000u) ? -INIT_STRENGTH : INIT_STRENGTH;
            }
        }
    }

    if (cpw) {
        int S = scnt[wid]; if (S > CAPS) S = CAPS;
        for (int t = lane; t < S; t += 64) out[rowoff + slist[wid][t]] = 0.f;
    }
}

// ---------------- kernel 3: finalize scalars ----------------
__global__ void final_kernel(const float* __restrict__ acc, float* __restrict__ out) {
    float c = 0.f, p = 0.f, z = 0.f;
    for (int s = 0; s < NSLOT; ++s) {
        c += acc[s * 4 + 0];
        p += acc[s * 4 + 1];
        z += acc[s * 4 + 2];
    }
    out[NN + 0] = c;
    out[NN + 1] = p;
    out[NN + 2] = z * (1.0f / (float)NN);
}

extern "C" void kernel_launch(void* const* d_in, const int* in_sizes, int n_in,
                              void* d_out, int out_size, void* d_ws, size_t ws_size,
                              hipStream_t stream) {
    const float* W   = (const float*)d_in[0];   // weight [4096,4096]
    const float* act = (const float*)d_in[1];   // activations [16,4096]
    float* out = (float*)d_out;                 // [w2 (N*N), created, pruned, sparsity]
    float* norm = (float*)d_ws;                 // [B][N]
    float* acc = norm + (size_t)B * N;          // 64 slots x 4 floats

    const size_t enc_off = (size_t)1 << 20;     // enc at +1 MB (norm/acc/rowcnt fit below)
    const size_t ws_needed = enc_off + (size_t)NN;  // 1 MB + 16 MB

    prep_kernel<<<N / 256, 256, 0, stream>>>(act, norm, acc);
    if (ws_size >= ws_needed) {
        int* rowcnt = (int*)(acc + NSLOT * 4);                  // 4096 x 8 x int2 = 256 KB
        unsigned char* enc = (unsigned char*)d_ws + enc_off;    // 16 MB
        stream_kernel<<<2048, 256, 0, stream>>>(W, norm, out, enc, rowcnt);
        select_kernel<<<N, 64, 0, stream>>>(enc, rowcnt, out, acc);
    } else {
        fused_kernel<<<N / R, 256, 0, stream>>>(W, norm, out, acc);
    }
    final_kernel<<<1, 1, 0, stream>>>(acc, out);
}

// Round 8
// 169.446 us; speedup vs baseline: 1.1309x; 1.1309x over previous
//
#include <hip/hip_runtime.h>
#include <math.h>

#define N 4096
#define B 16
#define NN (N * N)
#define R 4                    // rows per block (fallback fused kernel)
#define MAX_SYN 100
#define MIN_SYN 10
#define CREATE_T 0.3f
#define PRUNE_T 0.01f
#define INIT_STRENGTH 0.01f
#define EPS 1e-10f
#define BF_BASE 0x3E9Au        // bf16 code of smallest candidate magnitude (>0.3 RNE-rounds to >= 0x3E9A)
#define WEAK 0x7Fu             // enc code: weak existing synapse; cand codes are (1..126)|sign, never 0x7F
#define CAPM 96                // boundary (tie) list cap per row
#define CAPS 32                // small-weight list cap (fallback kernel only)
#define NSLOT 64

typedef float f32x4 __attribute__((ext_vector_type(4)));
typedef unsigned u32x4 __attribute__((ext_vector_type(4)));

// ---------------- kernel 1: per-column normalization + acc zeroing ----------------
__global__ void prep_kernel(const float* __restrict__ act,
                            float* __restrict__ norm,
                            float* __restrict__ acc) {
    int j = blockIdx.x * blockDim.x + threadIdx.x;
    if (blockIdx.x == 0 && threadIdx.x < NSLOT * 4) acc[threadIdx.x] = 0.f;
    if (j >= N) return;
    float a[B];
    float sum = 0.f;
#pragma unroll
    for (int b = 0; b < B; ++b) { a[b] = act[b * N + j]; sum += a[b]; }
    float mean = sum * (1.0f / B);
    float var = 0.f;
#pragma unroll
    for (int b = 0; b < B; ++b) { float c = a[b] - mean; var += c * c; }
    var *= (1.0f / (B - 1));   // ddof=1
    float sd = sqrtf(var);
    if (sd < 1e-8f) sd = 1e-8f;
    float inv = 1.0f / sd;
#pragma unroll
    for (int b = 0; b < B; ++b) norm[b * N + j] = (a[b] - mean) * inv;
}

// ---------------- kernel 2a: pure stream — corr + copy + u8 encode + counts ----------------
// NO LDS, NO barriers, NO hot-loop atomics. Block = 4 rows x 2048-col half, 256 threads.
// out copy is a PLAIN store (R7 used nontemporal: forces HBM-rate writes although the
// whole footprint is L3-resident — FETCH=34MB for 64MB W proves L3 absorption).
__global__ __launch_bounds__(256, 4) void stream_kernel(const float* __restrict__ W,
                                                        const float* __restrict__ norm,
                                                        float* __restrict__ out,
                                                        unsigned char* __restrict__ enc,
                                                        int* __restrict__ rowcnt) {
    const int tid = threadIdx.x;
    const int lane = tid & 63;
    const int wid = tid >> 6;               // 0..3
    const int half = blockIdx.x & 1;        // column half
    const int row0 = (blockIdx.x >> 1) * 4;
    const int cbase = half * 2048;

    // wave-uniform row vectors -> scalar loads
    float srow[4][B];
#pragma unroll
    for (int r = 0; r < 4; ++r)
#pragma unroll
        for (int b = 0; b < B; ++b) srow[r][b] = norm[b * N + row0 + r];

    int cnt_nz[4], cnt_cand[4], cnt_str[4];
#pragma unroll
    for (int r = 0; r < 4; ++r) { cnt_nz[r] = 0; cnt_cand[r] = 0; cnt_str[r] = 0; }

#pragma unroll
    for (int g = 0; g < 2; ++g) {
        const int j0 = cbase + g * 1024 + tid * 4;
        f32x4 w4[4];
#pragma unroll
        for (int r = 0; r < 4; ++r)
            w4[r] = __builtin_nontemporal_load((const f32x4*)(W + (size_t)(row0 + r) * N + j0));

        float cc[4][4];
#pragma unroll
        for (int r = 0; r < 4; ++r) { cc[r][0] = 0.f; cc[r][1] = 0.f; cc[r][2] = 0.f; cc[r][3] = 0.f; }
#pragma unroll
        for (int bh = 0; bh < 2; ++bh) {
            f32x4 nb[8];
#pragma unroll
            for (int b = 0; b < 8; ++b)
                nb[b] = *(const f32x4*)(norm + (bh * 8 + b) * N + j0);
#pragma unroll
            for (int r = 0; r < 4; ++r) {
#pragma unroll
                for (int b = 0; b < 8; ++b) {
                    float s = srow[r][bh * 8 + b];
                    cc[r][0] = fmaf(s, nb[b][0], cc[r][0]);
                    cc[r][1] = fmaf(s, nb[b][1], cc[r][1]);
                    cc[r][2] = fmaf(s, nb[b][2], cc[r][2]);
                    cc[r][3] = fmaf(s, nb[b][3], cc[r][3]);
                }
            }
        }

        // streaming copy W -> out (plain store: L2/L3 absorbs; fix-ups land in kernel 2b)
#pragma unroll
        for (int r = 0; r < 4; ++r)
            *(f32x4*)(out + (size_t)(row0 + r) * N + j0) = w4[r];

        // encode 4 codes per row into one u32, plain store (L2/L3 for 2b to read)
#pragma unroll
        for (int r = 0; r < 4; ++r) {
            unsigned pack = 0;
#pragma unroll
            for (int i = 0; i < 4; ++i) {
                float c = cc[r][i] * 0.0625f;       // /16
                float aw = fabsf(w4[r][i]);
                float ac = fabsf(c);
                int isnz = (aw > EPS) ? 1 : 0;
                int cand = ((ac > CREATE_T) && (aw < EPS)) ? 1 : 0;
                cnt_nz[r] += isnz;
                cnt_cand[r] += cand;
                cnt_str[r] += (aw >= PRUNE_T) ? 1 : 0;
                unsigned bits = __float_as_uint(ac);
                unsigned mag = (bits + 0x7FFFu + ((bits >> 16) & 1u)) >> 16;  // RNE bf16
                unsigned bin = (mag - BF_BASE) >> 1;
                if (bin > 125u) bin = 125u;          // safety; real max 107
                unsigned e = cand ? ((bin + 1u) | ((c < 0.f) ? 0x80u : 0u)) : 0u;
                if (isnz && aw < PRUNE_T) e = WEAK;  // weak existing synapse marker
                pack |= e << (8 * i);
            }
            *(unsigned*)(enc + (size_t)(row0 + r) * N + j0) = pack;
        }
    }

    // wave-reduce 8 packed counters, lane 0 stores to per-(row, slot) global ints
    int outv[8];
#pragma unroll
    for (int r = 0; r < 4; ++r) {
        outv[r] = cnt_nz[r] | (cnt_str[r] << 16);
        outv[4 + r] = cnt_cand[r];
    }
#pragma unroll
    for (int v = 0; v < 8; ++v) {
        int x = outv[v];
#pragma unroll
        for (int off = 32; off > 0; off >>= 1) x += __shfl_down(x, off, 64);
        outv[v] = x;
    }
    if (lane == 0) {
        const int slot = half * 4 + wid;    // 0..7
#pragma unroll
        for (int r = 0; r < 4; ++r) {
            const int base = ((row0 + r) * 8 + slot) * 2;
            rowcnt[base] = outv[r];
            rowcnt[base + 1] = outv[4 + r];
        }
    }
}

// ---------------- kernel 2b: 4 waves per row — selection + fix-ups + stats ----------------
// Grid 4096 x 256 threads: wave w owns column quarter [w*1024, (w+1)*1024).
// R7's 64-thr/1-wave-per-row version capped chip parallelism at 4096 waves (16/CU) and
// ran 46.5 us at 17% VALUBusy; 4x waves + 1/4 per-wave serial path fixes residency.
// All control values (nw/cpw/selh/cutbin/mm) are block-uniform -> barriers are safe.
__global__ __launch_bounds__(256) void select_kernel(const unsigned char* __restrict__ enc,
                                                     const int* __restrict__ rowcnt,
                                                     float* __restrict__ out,
                                                     float* __restrict__ acc) {
    __shared__ int hist[128];
    __shared__ unsigned mlist[CAPM];
    __shared__ int mcnt;

    const int tid = threadIdx.x;
    const int lane = tid & 63;
    const int wid = tid >> 6;          // column quarter
    const int row = blockIdx.x;
    const size_t rowoff = (size_t)row * N;

    // row counts (row-uniform -> scalar loads)
    int t = 0, C = 0;
#pragma unroll
    for (int s = 0; s < 8; ++s) {
        t += rowcnt[(row * 8 + s) * 2];
        C += rowcnt[(row * 8 + s) * 2 + 1];
    }
    const int nz = t & 0xFFFF;
    const int str = t >> 16;
    int nw = 0;
    if (nz < MAX_SYN) { int room = MAX_SYN - nz; nw = C < room ? C : room; }
    const int cpw = ((str + nw) > MIN_SYN) ? 1 : 0;
    const bool selh = (nw > 0) && (nw < C);

    if (tid < 128) hist[tid] = 0;
    if (tid == 128) mcnt = 0;
    if (tid == 255) {
        int strong = str + nw;
        float* slot = acc + (row & (NSLOT - 1)) * 4;
        atomicAdd(slot + 0, (float)nw);
        atomicAdd(slot + 1, (float)(cpw ? (N - strong) : 0));
        atomicAdd(slot + 2, (float)((N - nz - nw) + (cpw ? (nz - str) : 0)));
    }

    // own quarter's codes: 16 bytes per lane (coalesced 1 KB per wave)
    const u32x4 ev = *(const u32x4*)(enc + rowoff + (size_t)wid * 1024 + (size_t)lane * 16);

    __syncthreads();   // hist/mcnt init complete

    if (selh) {
#pragma unroll
        for (int d = 0; d < 4; ++d) {
            unsigned u = ev[d];
            if (!u) continue;
#pragma unroll
            for (int i = 0; i < 4; ++i) {
                unsigned e = (u >> (8 * i)) & 0xFFu;
                if (e && e != WEAK) atomicAdd(&hist[(e & 0x7Fu) - 1u], 1);
            }
        }
    }
    __syncthreads();   // histogram complete

    int cutbin = (nw > 0) ? -1 : 0x7FFFFFFF;   // nw==C>0: everything creates; nw==0: nothing
    int mm = 0;
    if (selh) {
        // per-wave redundant suffix-scan over 128 bins (all waves compute identical result)
        int h[2], v[2];
#pragma unroll
        for (int q = 0; q < 2; ++q) { h[q] = hist[q * 64 + lane]; v[q] = h[q]; }
#pragma unroll
        for (int off = 1; off < 64; off <<= 1) {
#pragma unroll
            for (int q = 0; q < 2; ++q) {
                int tt = __shfl_down(v[q], off, 64);
                v[q] += (lane + off < 64) ? tt : 0;
            }
        }
        int T1 = __shfl(v[1], 0, 64);           // total of bins 64..127
        int cb = 128;
#pragma unroll
        for (int q = 0; q < 2; ++q) {
            int S = v[q] + (q == 0 ? T1 : 0);   // # entries with bin >= q*64+lane
            if (S >= nw && S - h[q] < nw) { cb = q * 64 + lane; mm = nw - (S - h[q]); }
        }
#pragma unroll
        for (int off = 1; off < 64; off <<= 1) {
            int cb2 = __shfl_xor(cb, off, 64);
            int mm2 = __shfl_xor(mm, off, 64);
            cb = cb < cb2 ? cb : cb2;
            mm = mm > mm2 ? mm : mm2;
        }
        cutbin = cb;
    }

    // classify own quarter: creates above cut, boundary ties to mlist, weak prunes inline
    if (nw > 0 || cpw) {
#pragma unroll
        for (int d = 0; d < 4; ++d) {
            unsigned u = ev[d];
            if (!u) continue;
#pragma unroll
            for (int i = 0; i < 4; ++i) {
                unsigned e = (u >> (8 * i)) & 0xFFu;
                if (!e) continue;
                const int col = wid * 1024 + lane * 16 + d * 4 + i;
                if (e == WEAK) {
                    if (cpw) out[rowoff + col] = 0.f;
                } else if (nw > 0) {
                    int bin = (int)(e & 0x7Fu) - 1;
                    if (bin > cutbin) {
                        out[rowoff + col] = (e & 0x80u) ? -INIT_STRENGTH : INIT_STRENGTH;
                    } else if (bin == cutbin) {
                        int idx = atomicAdd(&mcnt, 1);
                        if (idx < CAPM) mlist[idx] = (e << 16) | (unsigned)col;
                    }
                }
            }
        }
    }
    __syncthreads();   // mlist complete

    // ties: take mm smallest columns in the cut bin (all 256 threads share the ranking)
    if (mm > 0) {
        int L = mcnt; if (L > CAPM) L = CAPM;
        for (int k = tid; k < L; k += 256) {
            unsigned me = mlist[k];
            int mycol = (int)(me & 0xFFFFu);
            int rk = 0;
            for (int t2 = 0; t2 < L; ++t2)
                rk += ((int)(mlist[t2] & 0xFFFFu) < mycol) ? 1 : 0;
            if (rk < mm)
                out[rowoff + mycol] = (me & 0x800000u) ? -INIT_STRENGTH : INIT_STRENGTH;
        }
    }
}

// ---------------- fallback fused kernel (round-5, proven): used if ws too small ----------------
__global__ __launch_bounds__(256, 4) void fused_kernel(const float* __restrict__ W,
                                                       const float* __restrict__ norm,
                                                       float* __restrict__ out,
                                                       float* __restrict__ acc) {
    __shared__ unsigned char enc[R][N];
    __shared__ int hist[R][128];
    __shared__ unsigned mlist[R][CAPM];
    __shared__ unsigned short slist[R][CAPS];
    __shared__ int scnt[R];
    __shared__ int mcnt[R];
    __shared__ int red[4][8];

    const int tid = threadIdx.x;
    const int lane = tid & 63;
    const int wid = tid >> 6;
    const int row0 = blockIdx.x * R;

    if (tid < R) { scnt[tid] = 0; mcnt[tid] = 0; }
#pragma unroll
    for (int q = 0; q < 2; ++q) ((int*)hist)[q * 256 + tid] = 0;

    float srow[R][B];
#pragma unroll
    for (int r = 0; r < R; ++r)
#pragma unroll
        for (int b = 0; b < B; ++b) srow[r][b] = norm[b * N + row0 + r];

    __syncthreads();

    int cnt_nz[R], cnt_cand[R], cnt_str[R];
#pragma unroll
    for (int r = 0; r < R; ++r) { cnt_nz[r] = 0; cnt_cand[r] = 0; cnt_str[r] = 0; }

#pragma unroll
    for (int g = 0; g < 4; ++g) {
        const int j0 = g * 1024 + tid * 4;
        f32x4 w4[R];
#pragma unroll
        for (int r = 0; r < R; ++r)
            w4[r] = __builtin_nontemporal_load((const f32x4*)(W + (size_t)(row0 + r) * N + j0));
        float cc[R][4];
#pragma unroll
        for (int r = 0; r < R; ++r) { cc[r][0] = 0.f; cc[r][1] = 0.f; cc[r][2] = 0.f; cc[r][3] = 0.f; }
#pragma unroll
        for (int bh = 0; bh < 2; ++bh) {
            f32x4 nb[8];
#pragma unroll
            for (int b = 0; b < 8; ++b)
                nb[b] = *(const f32x4*)(norm + (bh * 8 + b) * N + j0);
#pragma unroll
            for (int r = 0; r < R; ++r) {
#pragma unroll
                for (int b = 0; b < 8; ++b) {
                    float s = srow[r][bh * 8 + b];
                    cc[r][0] = fmaf(s, nb[b][0], cc[r][0]);
                    cc[r][1] = fmaf(s, nb[b][1], cc[r][1]);
                    cc[r][2] = fmaf(s, nb[b][2], cc[r][2]);
                    cc[r][3] = fmaf(s, nb[b][3], cc[r][3]);
                }
            }
        }
#pragma unroll
        for (int r = 0; r < R; ++r)
            __builtin_nontemporal_store(w4[r], (f32x4*)(out + (size_t)(row0 + r) * N + j0));
#pragma unroll
        for (int r = 0; r < R; ++r) {
            unsigned pack = 0;
#pragma unroll
            for (int i = 0; i < 4; ++i) {
                float c = cc[r][i] * 0.0625f;
                float aw = fabsf(w4[r][i]);
                float ac = fabsf(c);
                int isnz = (aw > EPS) ? 1 : 0;
                int cand = ((ac > CREATE_T) && (aw < EPS)) ? 1 : 0;
                cnt_nz[r] += isnz;
                cnt_cand[r] += cand;
                cnt_str[r] += (aw >= PRUNE_T) ? 1 : 0;
                if (isnz && aw < PRUNE_T) {
                    int idx = atomicAdd(&scnt[r], 1);
                    if (idx < CAPS) slist[r][idx] = (unsigned short)(j0 + i);
                }
                unsigned bits = __float_as_uint(ac);
                unsigned mag = (bits + 0x7FFFu + ((bits >> 16) & 1u)) >> 16;
                unsigned bin = (mag - BF_BASE) >> 1;
                if (bin > 125u) bin = 125u;
                unsigned e = cand ? ((bin + 1u) | ((c < 0.f) ? 0x80u : 0u)) : 0u;
                pack |= e << (8 * i);
            }
            *(unsigned*)&enc[r][j0] = pack;
        }
    }

    int vals[8];
#pragma unroll
    for (int r = 0; r < R; ++r) {
        vals[r] = cnt_nz[r] | (cnt_str[r] << 16);
        vals[4 + r] = cnt_cand[r];
    }
#pragma unroll
    for (int v = 0; v < 8; ++v) {
        int x = vals[v];
#pragma unroll
        for (int off = 32; off > 0; off >>= 1) x += __shfl_down(x, off, 64);
        if (lane == 0) red[wid][v] = x;
    }
    __syncthreads();

    if (tid == 0) {
        int created_total = 0, pruned_total = 0, zeros_total = 0;
#pragma unroll
        for (int r = 0; r < R; ++r) {
            int t = red[0][r] + red[1][r] + red[2][r] + red[3][r];
            int C = red[0][4 + r] + red[1][4 + r] + red[2][4 + r] + red[3][4 + r];
            int nz = t & 0xFFFF, str = t >> 16;
            int n = 0;
            if (nz < MAX_SYN) { int room = MAX_SYN - nz; n = C < room ? C : room; }
            int strong = str + n;
            int cp = (strong > MIN_SYN) ? 1 : 0;
            created_total += n;
            pruned_total += cp ? (N - strong) : 0;
            zeros_total += (N - nz - n) + (cp ? (nz - str) : 0);
        }
        float* slot = acc + (blockIdx.x & (NSLOT - 1)) * 4;
        atomicAdd(slot + 0, (float)created_total);
        atomicAdd(slot + 1, (float)pruned_total);
        atomicAdd(slot + 2, (float)zeros_total);
    }

    const int tw = red[0][wid] + red[1][wid] + red[2][wid] + red[3][wid];
    const int nzw = tw & 0xFFFF;
    const int strw = tw >> 16;
    const int Cw = red[0][4 + wid] + red[1][4 + wid] + red[2][4 + wid] + red[3][4 + wid];
    int nw = 0;
    if (nzw < MAX_SYN) { int room = MAX_SYN - nzw; nw = Cw < room ? Cw : room; }
    const int cpw = ((strw + nw) > MIN_SYN) ? 1 : 0;
    const size_t rowoff = (size_t)(row0 + wid) * N;
    const bool selh = (nw > 0) && (nw < Cw);

    if (selh) {
#pragma unroll
        for (int t = 0; t < 16; ++t) {
            unsigned ev = *(const unsigned*)&enc[wid][(t * 64 + lane) * 4];
            if (!ev) continue;
#pragma unroll
            for (int i = 0; i < 4; ++i) {
                unsigned e = (ev >> (8 * i)) & 0xFFu;
                if (e) atomicAdd(&hist[wid][(e & 0x7Fu) - 1u], 1);
            }
        }
    }

    int cutbin = (nw > 0) ? -1 : 0x7FFFFFFF;
    int mm = 0;
    if (selh) {
        int h[2], v[2];
#pragma unroll
        for (int q = 0; q < 2; ++q) { h[q] = hist[wid][q * 64 + lane]; v[q] = h[q]; }
#pragma unroll
        for (int off = 1; off < 64; off <<= 1) {
#pragma unroll
            for (int q = 0; q < 2; ++q) {
                int t = __shfl_down(v[q], off, 64);
                v[q] += (lane + off < 64) ? t : 0;
            }
        }
        int T1 = __shfl(v[1], 0, 64);
        int cb = 128;
#pragma unroll
        for (int q = 0; q < 2; ++q) {
            int S = v[q] + (q == 0 ? T1 : 0);
            if (S >= nw && S - h[q] < nw) { cb = q * 64 + lane; mm = nw - (S - h[q]); }
        }
#pragma unroll
        for (int off = 1; off < 64; off <<= 1) {
            int cb2 = __shfl_xor(cb, off, 64);
            int mm2 = __shfl_xor(mm, off, 64);
            cb = cb < cb2 ? cb : cb2;
            mm = mm > mm2 ? mm : mm2;
        }
        cutbin = cb;
    }

    if (nw > 0) {
#pragma unroll
        for (int t = 0; t < 16; ++t) {
            const int si = (t * 64 + lane) * 4;
            unsigned ev = *(const unsigned*)&enc[wid][si];
            if (!ev) continue;
#pragma unroll
            for (int i = 0; i < 4; ++i) {
                unsigned e = (ev >> (8 * i)) & 0xFFu;
                int bin = (int)(e & 0x7Fu) - 1;
                if (e && bin > cutbin) {
                    out[rowoff + si + i] = (e & 0x80u) ? -INIT_STRENGTH : INIT_STRENGTH;
                } else if (e && bin == cutbin) {
                    int idx = atomicAdd(&mcnt[wid], 1);
                    if (idx < CAPM) mlist[wid][idx] = (e << 16) | (unsigned)(si + i);
                }
            }
        }
        int L = mcnt[wid]; if (L > CAPM) L = CAPM;
        for (int t0 = 0; t0 < L; t0 += 64) {
            int t = t0 + lane;
            if (t < L) {
                unsigned me = mlist[wid][t];
                int mycol = (int)(me & 0xFFFFu);
                int rk = 0;
                for (int t2 = 0; t2 < L; ++t2)
                    rk += ((int)(mlist[wid][t2] & 0xFFFFu) < mycol) ? 1 : 0;
                if (rk < mm)
                    out[rowoff + mycol] = (me & 0x800000u) ? -INIT_STRENGTH : INIT_STRENGTH;
            }
        }
    }

    if (cpw) {
        int S = scnt[wid]; if (S > CAPS) S = CAPS;
        for (int t = lane; t < S; t += 64) out[rowoff + slist[wid][t]] = 0.f;
    }
}

// ---------------- kernel 3: finalize scalars ----------------
__global__ void final_kernel(const float* __restrict__ acc, float* __restrict__ out) {
    float c = 0.f, p = 0.f, z = 0.f;
    for (int s = 0; s < NSLOT; ++s) {
        c += acc[s * 4 + 0];
        p += acc[s * 4 + 1];
        z += acc[s * 4 + 2];
    }
    out[NN + 0] = c;
    out[NN + 1] = p;
    out[NN + 2] = z * (1.0f / (float)NN);
}

extern "C" void kernel_launch(void* const* d_in, const int* in_sizes, int n_in,
                              void* d_out, int out_size, void* d_ws, size_t ws_size,
                              hipStream_t stream) {
    const float* W   = (const float*)d_in[0];   // weight [4096,4096]
    const float* act = (const float*)d_in[1];   // activations [16,4096]
    float* out = (float*)d_out;                 // [w2 (N*N), created, pruned, sparsity]
    float* norm = (float*)d_ws;                 // [B][N]
    float* acc = norm + (size_t)B * N;          // 64 slots x 4 floats

    const size_t enc_off = (size_t)1 << 20;     // enc at +1 MB (norm/acc/rowcnt fit below)
    const size_t ws_needed = enc_off + (size_t)NN;  // 1 MB + 16 MB

    prep_kernel<<<N / 256, 256, 0, stream>>>(act, norm, acc);
    if (ws_size >= ws_needed) {
        int* rowcnt = (int*)(acc + NSLOT * 4);                  // 4096 x 8 x int2 = 256 KB
        unsigned char* enc = (unsigned char*)d_ws + enc_off;    // 16 MB
        stream_kernel<<<2048, 256, 0, stream>>>(W, norm, out, enc, rowcnt);
        select_kernel<<<N, 256, 0, stream>>>(enc, rowcnt, out, acc);
    } else {
        fused_kernel<<<N / R, 256, 0, stream>>>(W, norm, out, acc);
    }
    final_kernel<<<1, 1, 0, stream>>>(acc, out);
}

// Round 9
// 166.554 us; speedup vs baseline: 1.1506x; 1.0174x over previous
//
#include <hip/hip_runtime.h>
#include <math.h>

#define N 4096
#define B 16
#define NN (N * N)
#define R 4                    // rows per block (fallback fused kernel)
#define MAX_SYN 100
#define MIN_SYN 10
#define CREATE_T 0.3f
#define PRUNE_T 0.01f
#define INIT_STRENGTH 0.01f
#define EPS 1e-10f
#define BF_BASE 0x3E9Au        // bf16 code of smallest candidate magnitude (>0.3 RNE-rounds to >= 0x3E9A)
#define WEAK 0x7Fu             // enc code: weak existing synapse; cand codes are (1..126)|sign, never 0x7F
#define CAPM 96                // boundary (tie) list cap per row
#define CAPS 32                // small-weight list cap (fallback kernel only)
#define NSLOT 64

typedef float f32x4 __attribute__((ext_vector_type(4)));
typedef unsigned u32x4 __attribute__((ext_vector_type(4)));

// ---------------- kernel 1: per-column normalization + acc zeroing ----------------
__global__ void prep_kernel(const float* __restrict__ act,
                            float* __restrict__ norm,
                            float* __restrict__ acc) {
    int j = blockIdx.x * blockDim.x + threadIdx.x;
    if (blockIdx.x == 0 && threadIdx.x < NSLOT * 4) acc[threadIdx.x] = 0.f;
    if (j >= N) return;
    float a[B];
    float sum = 0.f;
#pragma unroll
    for (int b = 0; b < B; ++b) { a[b] = act[b * N + j]; sum += a[b]; }
    float mean = sum * (1.0f / B);
    float var = 0.f;
#pragma unroll
    for (int b = 0; b < B; ++b) { float c = a[b] - mean; var += c * c; }
    var *= (1.0f / (B - 1));   // ddof=1
    float sd = sqrtf(var);
    if (sd < 1e-8f) sd = 1e-8f;
    float inv = 1.0f / sd;
#pragma unroll
    for (int b = 0; b < B; ++b) norm[b * N + j] = (a[b] - mean) * inv;
}

// ---------------- kernel 2a: pure stream — corr + copy + u8 encode + counts ----------------
// NO LDS, NO barriers, NO hot-loop atomics. Block = 4 rows x 1024-col quarter, 256 thr.
// Grid 4096 = 16 blocks/CU available (2x oversubscription of the 32-wave/CU limit) so the
// scheduler can always backfill — R8's grid 2048 was exactly 32 waves/CU with zero slack
// and measured only ~29% occupancy / 45% VALUBusy (latency-bound). No waves-per-EU hint:
// R4 showed tight VGPR caps spill; plain (256) leaves the allocator free (~60 VGPR).
__global__ __launch_bounds__(256) void stream_kernel(const float* __restrict__ W,
                                                     const float* __restrict__ norm,
                                                     float* __restrict__ out,
                                                     unsigned char* __restrict__ enc,
                                                     int* __restrict__ rowcnt) {
    const int tid = threadIdx.x;
    const int lane = tid & 63;
    const int wid = tid >> 6;               // 0..3
    const int qb = blockIdx.x & 3;          // column quarter
    const int row0 = (blockIdx.x >> 2) * 4;
    const int j0 = qb * 1024 + tid * 4;

    // wave-uniform row vectors -> scalar loads
    float srow[4][B];
#pragma unroll
    for (int r = 0; r < 4; ++r)
#pragma unroll
        for (int b = 0; b < B; ++b) srow[r][b] = norm[b * N + row0 + r];

    int cnt_nz[4], cnt_cand[4], cnt_str[4];
#pragma unroll
    for (int r = 0; r < 4; ++r) { cnt_nz[r] = 0; cnt_cand[r] = 0; cnt_str[r] = 0; }

    f32x4 w4[4];
#pragma unroll
    for (int r = 0; r < 4; ++r)
        w4[r] = __builtin_nontemporal_load((const f32x4*)(W + (size_t)(row0 + r) * N + j0));

    float cc[4][4];
#pragma unroll
    for (int r = 0; r < 4; ++r) { cc[r][0] = 0.f; cc[r][1] = 0.f; cc[r][2] = 0.f; cc[r][3] = 0.f; }
#pragma unroll
    for (int bh = 0; bh < 2; ++bh) {
        f32x4 nb[8];
#pragma unroll
        for (int b = 0; b < 8; ++b)
            nb[b] = *(const f32x4*)(norm + (bh * 8 + b) * N + j0);
#pragma unroll
        for (int r = 0; r < 4; ++r) {
#pragma unroll
            for (int b = 0; b < 8; ++b) {
                float s = srow[r][bh * 8 + b];
                cc[r][0] = fmaf(s, nb[b][0], cc[r][0]);
                cc[r][1] = fmaf(s, nb[b][1], cc[r][1]);
                cc[r][2] = fmaf(s, nb[b][2], cc[r][2]);
                cc[r][3] = fmaf(s, nb[b][3], cc[r][3]);
            }
        }
    }

    // streaming copy W -> out (plain store: L2/L3 absorbs; fix-ups land in kernel 2b)
#pragma unroll
    for (int r = 0; r < 4; ++r)
        *(f32x4*)(out + (size_t)(row0 + r) * N + j0) = w4[r];

    // encode 4 codes per row into one u32, plain store (L2/L3 for 2b to read)
#pragma unroll
    for (int r = 0; r < 4; ++r) {
        unsigned pack = 0;
#pragma unroll
        for (int i = 0; i < 4; ++i) {
            float c = cc[r][i] * 0.0625f;       // /16
            float aw = fabsf(w4[r][i]);
            float ac = fabsf(c);
            int isnz = (aw > EPS) ? 1 : 0;
            int cand = ((ac > CREATE_T) && (aw < EPS)) ? 1 : 0;
            cnt_nz[r] += isnz;
            cnt_cand[r] += cand;
            cnt_str[r] += (aw >= PRUNE_T) ? 1 : 0;
            unsigned bits = __float_as_uint(ac);
            unsigned mag = (bits + 0x7FFFu + ((bits >> 16) & 1u)) >> 16;  // RNE bf16
            unsigned bin = (mag - BF_BASE) >> 1;
            if (bin > 125u) bin = 125u;          // safety; real max 107
            unsigned e = cand ? ((bin + 1u) | ((c < 0.f) ? 0x80u : 0u)) : 0u;
            if (isnz && aw < PRUNE_T) e = WEAK;  // weak existing synapse marker
            pack |= e << (8 * i);
        }
        *(unsigned*)(enc + (size_t)(row0 + r) * N + j0) = pack;
    }

    // wave-reduce 8 packed counters, lane 0 stores to per-(row, slot) global ints
    int outv[8];
#pragma unroll
    for (int r = 0; r < 4; ++r) {
        outv[r] = cnt_nz[r] | (cnt_str[r] << 16);
        outv[4 + r] = cnt_cand[r];
    }
#pragma unroll
    for (int v = 0; v < 8; ++v) {
        int x = outv[v];
#pragma unroll
        for (int off = 32; off > 0; off >>= 1) x += __shfl_down(x, off, 64);
        outv[v] = x;
    }
    if (lane == 0) {
        const int slot = qb * 4 + wid;      // 0..15
#pragma unroll
        for (int r = 0; r < 4; ++r) {
            const int base = ((row0 + r) * 16 + slot) * 2;
            rowcnt[base] = outv[r];
            rowcnt[base + 1] = outv[4 + r];
        }
    }
}

// ---------------- kernel 2b: 4 waves per row — selection + fix-ups + stats ----------------
// Grid 4096 x 256 threads: wave w owns column quarter [w*1024, (w+1)*1024).
// All control values (nw/cpw/selh/cutbin/mm) are block-uniform -> barriers are safe.
__global__ __launch_bounds__(256) void select_kernel(const unsigned char* __restrict__ enc,
                                                     const int* __restrict__ rowcnt,
                                                     float* __restrict__ out,
                                                     float* __restrict__ acc) {
    __shared__ int hist[128];
    __shared__ unsigned mlist[CAPM];
    __shared__ int mcnt;

    const int tid = threadIdx.x;
    const int lane = tid & 63;
    const int wid = tid >> 6;          // column quarter
    const int row = blockIdx.x;
    const size_t rowoff = (size_t)row * N;

    // row counts (row-uniform -> scalar loads)
    int t = 0, C = 0;
#pragma unroll
    for (int s = 0; s < 16; ++s) {
        t += rowcnt[(row * 16 + s) * 2];
        C += rowcnt[(row * 16 + s) * 2 + 1];
    }
    const int nz = t & 0xFFFF;
    const int str = t >> 16;
    int nw = 0;
    if (nz < MAX_SYN) { int room = MAX_SYN - nz; nw = C < room ? C : room; }
    const int cpw = ((str + nw) > MIN_SYN) ? 1 : 0;
    const bool selh = (nw > 0) && (nw < C);

    if (tid < 128) hist[tid] = 0;
    if (tid == 128) mcnt = 0;
    if (tid == 255) {
        int strong = str + nw;
        float* slot = acc + (row & (NSLOT - 1)) * 4;
        atomicAdd(slot + 0, (float)nw);
        atomicAdd(slot + 1, (float)(cpw ? (N - strong) : 0));
        atomicAdd(slot + 2, (float)((N - nz - nw) + (cpw ? (nz - str) : 0)));
    }

    // own quarter's codes: 16 bytes per lane (coalesced 1 KB per wave)
    const u32x4 ev = *(const u32x4*)(enc + rowoff + (size_t)wid * 1024 + (size_t)lane * 16);

    __syncthreads();   // hist/mcnt init complete

    if (selh) {
#pragma unroll
        for (int d = 0; d < 4; ++d) {
            unsigned u = ev[d];
            if (!u) continue;
#pragma unroll
            for (int i = 0; i < 4; ++i) {
                unsigned e = (u >> (8 * i)) & 0xFFu;
                if (e && e != WEAK) atomicAdd(&hist[(e & 0x7Fu) - 1u], 1);
            }
        }
    }
    __syncthreads();   // histogram complete

    int cutbin = (nw > 0) ? -1 : 0x7FFFFFFF;   // nw==C>0: everything creates; nw==0: nothing
    int mm = 0;
    if (selh) {
        // per-wave redundant suffix-scan over 128 bins (all waves compute identical result)
        int h[2], v[2];
#pragma unroll
        for (int q = 0; q < 2; ++q) { h[q] = hist[q * 64 + lane]; v[q] = h[q]; }
#pragma unroll
        for (int off = 1; off < 64; off <<= 1) {
#pragma unroll
            for (int q = 0; q < 2; ++q) {
                int tt = __shfl_down(v[q], off, 64);
                v[q] += (lane + off < 64) ? tt : 0;
            }
        }
        int T1 = __shfl(v[1], 0, 64);           // total of bins 64..127
        int cb = 128;
#pragma unroll
        for (int q = 0; q < 2; ++q) {
            int S = v[q] + (q == 0 ? T1 : 0);   // # entries with bin >= q*64+lane
            if (S >= nw && S - h[q] < nw) { cb = q * 64 + lane; mm = nw - (S - h[q]); }
        }
#pragma unroll
        for (int off = 1; off < 64; off <<= 1) {
            int cb2 = __shfl_xor(cb, off, 64);
            int mm2 = __shfl_xor(mm, off, 64);
            cb = cb < cb2 ? cb : cb2;
            mm = mm > mm2 ? mm : mm2;
        }
        cutbin = cb;
    }

    // classify own quarter: creates above cut, boundary ties to mlist, weak prunes inline
    if (nw > 0 || cpw) {
#pragma unroll
        for (int d = 0; d < 4; ++d) {
            unsigned u = ev[d];
            if (!u) continue;
#pragma unroll
            for (int i = 0; i < 4; ++i) {
                unsigned e = (u >> (8 * i)) & 0xFFu;
                if (!e) continue;
                const int col = wid * 1024 + lane * 16 + d * 4 + i;
                if (e == WEAK) {
                    if (cpw) out[rowoff + col] = 0.f;
                } else if (nw > 0) {
                    int bin = (int)(e & 0x7Fu) - 1;
                    if (bin > cutbin) {
                        out[rowoff + col] = (e & 0x80u) ? -INIT_STRENGTH : INIT_STRENGTH;
                    } else if (bin == cutbin) {
                        int idx = atomicAdd(&mcnt, 1);
                        if (idx < CAPM) mlist[idx] = (e << 16) | (unsigned)col;
                    }
                }
            }
        }
    }
    __syncthreads();   // mlist complete

    // ties: take mm smallest columns in the cut bin (all 256 threads share the ranking)
    if (mm > 0) {
        int L = mcnt; if (L > CAPM) L = CAPM;
        for (int k = tid; k < L; k += 256) {
            unsigned me = mlist[k];
            int mycol = (int)(me & 0xFFFFu);
            int rk = 0;
            for (int t2 = 0; t2 < L; ++t2)
                rk += ((int)(mlist[t2] & 0xFFFFu) < mycol) ? 1 : 0;
            if (rk < mm)
                out[rowoff + mycol] = (me & 0x800000u) ? -INIT_STRENGTH : INIT_STRENGTH;
        }
    }
}

// ---------------- fallback fused kernel (round-5, proven): used if ws too small ----------------
__global__ __launch_bounds__(256, 4) void fused_kernel(const float* __restrict__ W,
                                                       const float* __restrict__ norm,
                                                       float* __restrict__ out,
                                                       float* __restrict__ acc) {
    __shared__ unsigned char enc[R][N];
    __shared__ int hist[R][128];
    __shared__ unsigned mlist[R][CAPM];
    __shared__ unsigned short slist[R][CAPS];
    __shared__ int scnt[R];
    __shared__ int mcnt[R];
    __shared__ int red[4][8];

    const int tid = threadIdx.x;
    const int lane = tid & 63;
    const int wid = tid >> 6;
    const int row0 = blockIdx.x * R;

    if (tid < R) { scnt[tid] = 0; mcnt[tid] = 0; }
#pragma unroll
    for (int q = 0; q < 2; ++q) ((int*)hist)[q * 256 + tid] = 0;

    float srow[R][B];
#pragma unroll
    for (int r = 0; r < R; ++r)
#pragma unroll
        for (int b = 0; b < B; ++b) srow[r][b] = norm[b * N + row0 + r];

    __syncthreads();

    int cnt_nz[R], cnt_cand[R], cnt_str[R];
#pragma unroll
    for (int r = 0; r < R; ++r) { cnt_nz[r] = 0; cnt_cand[r] = 0; cnt_str[r] = 0; }

#pragma unroll
    for (int g = 0; g < 4; ++g) {
        const int j0 = g * 1024 + tid * 4;
        f32x4 w4[R];
#pragma unroll
        for (int r = 0; r < R; ++r)
            w4[r] = __builtin_nontemporal_load((const f32x4*)(W + (size_t)(row0 + r) * N + j0));
        float cc[R][4];
#pragma unroll
        for (int r = 0; r < R; ++r) { cc[r][0] = 0.f; cc[r][1] = 0.f; cc[r][2] = 0.f; cc[r][3] = 0.f; }
#pragma unroll
        for (int bh = 0; bh < 2; ++bh) {
            f32x4 nb[8];
#pragma unroll
            for (int b = 0; b < 8; ++b)
                nb[b] = *(const f32x4*)(norm + (bh * 8 + b) * N + j0);
#pragma unroll
            for (int r = 0; r < R; ++r) {
#pragma unroll
                for (int b = 0; b < 8; ++b) {
                    float s = srow[r][bh * 8 + b];
                    cc[r][0] = fmaf(s, nb[b][0], cc[r][0]);
                    cc[r][1] = fmaf(s, nb[b][1], cc[r][1]);
                    cc[r][2] = fmaf(s, nb[b][2], cc[r][2]);
                    cc[r][3] = fmaf(s, nb[b][3], cc[r][3]);
                }
            }
        }
#pragma unroll
        for (int r = 0; r < R; ++r)
            __builtin_nontemporal_store(w4[r], (f32x4*)(out + (size_t)(row0 + r) * N + j0));
#pragma unroll
        for (int r = 0; r < R; ++r) {
            unsigned pack = 0;
#pragma unroll
            for (int i = 0; i < 4; ++i) {
                float c = cc[r][i] * 0.0625f;
                float aw = fabsf(w4[r][i]);
                float ac = fabsf(c);
                int isnz = (aw > EPS) ? 1 : 0;
                int cand = ((ac > CREATE_T) && (aw < EPS)) ? 1 : 0;
                cnt_nz[r] += isnz;
                cnt_cand[r] += cand;
                cnt_str[r] += (aw >= PRUNE_T) ? 1 : 0;
                if (isnz && aw < PRUNE_T) {
                    int idx = atomicAdd(&scnt[r], 1);
                    if (idx < CAPS) slist[r][idx] = (unsigned short)(j0 + i);
                }
                unsigned bits = __float_as_uint(ac);
                unsigned mag = (bits + 0x7FFFu + ((bits >> 16) & 1u)) >> 16;
                unsigned bin = (mag - BF_BASE) >> 1;
                if (bin > 125u) bin = 125u;
                unsigned e = cand ? ((bin + 1u) | ((c < 0.f) ? 0x80u : 0u)) : 0u;
                pack |= e << (8 * i);
            }
            *(unsigned*)&enc[r][j0] = pack;
        }
    }

    int vals[8];
#pragma unroll
    for (int r = 0; r < R; ++r) {
        vals[r] = cnt_nz[r] | (cnt_str[r] << 16);
        vals[4 + r] = cnt_cand[r];
    }
#pragma unroll
    for (int v = 0; v < 8; ++v) {
        int x = vals[v];
#pragma unroll
        for (int off = 32; off > 0; off >>= 1) x += __shfl_down(x, off, 64);
        if (lane == 0) red[wid][v] = x;
    }
    __syncthreads();

    if (tid == 0) {
        int created_total = 0, pruned_total = 0, zeros_total = 0;
#pragma unroll
        for (int r = 0; r < R; ++r) {
            int t = red[0][r] + red[1][r] + red[2][r] + red[3][r];
            int C = red[0][4 + r] + red[1][4 + r] + red[2][4 + r] + red[3][4 + r];
            int nz = t & 0xFFFF, str = t >> 16;
            int n = 0;
            if (nz < MAX_SYN) { int room = MAX_SYN - nz; n = C < room ? C : room; }
            int strong = str + n;
            int cp = (strong > MIN_SYN) ? 1 : 0;
            created_total += n;
            pruned_total += cp ? (N - strong) : 0;
            zeros_total += (N - nz - n) + (cp ? (nz - str) : 0);
        }
        float* slot = acc + (blockIdx.x & (NSLOT - 1)) * 4;
        atomicAdd(slot + 0, (float)created_total);
        atomicAdd(slot + 1, (float)pruned_total);
        atomicAdd(slot + 2, (float)zeros_total);
    }

    const int tw = red[0][wid] + red[1][wid] + red[2][wid] + red[3][wid];
    const int nzw = tw & 0xFFFF;
    const int strw = tw >> 16;
    const int Cw = red[0][4 + wid] + red[1][4 + wid] + red[2][4 + wid] + red[3][4 + wid];
    int nw = 0;
    if (nzw < MAX_SYN) { int room = MAX_SYN - nzw; nw = Cw < room ? Cw : room; }
    const int cpw = ((strw + nw) > MIN_SYN) ? 1 : 0;
    const size_t rowoff = (size_t)(row0 + wid) * N;
    const bool selh = (nw > 0) && (nw < Cw);

    if (selh) {
#pragma unroll
        for (int t = 0; t < 16; ++t) {
            unsigned ev = *(const unsigned*)&enc[wid][(t * 64 + lane) * 4];
            if (!ev) continue;
#pragma unroll
            for (int i = 0; i < 4; ++i) {
                unsigned e = (ev >> (8 * i)) & 0xFFu;
                if (e) atomicAdd(&hist[wid][(e & 0x7Fu) - 1u], 1);
            }
        }
    }

    int cutbin = (nw > 0) ? -1 : 0x7FFFFFFF;
    int mm = 0;
    if (selh) {
        int h[2], v[2];
#pragma unroll
        for (int q = 0; q < 2; ++q) { h[q] = hist[wid][q * 64 + lane]; v[q] = h[q]; }
#pragma unroll
        for (int off = 1; off < 64; off <<= 1) {
#pragma unroll
            for (int q = 0; q < 2; ++q) {
                int t = __shfl_down(v[q], off, 64);
                v[q] += (lane + off < 64) ? t : 0;
            }
        }
        int T1 = __shfl(v[1], 0, 64);
        int cb = 128;
#pragma unroll
        for (int q = 0; q < 2; ++q) {
            int S = v[q] + (q == 0 ? T1 : 0);
            if (S >= nw && S - h[q] < nw) { cb = q * 64 + lane; mm = nw - (S - h[q]); }
        }
#pragma unroll
        for (int off = 1; off < 64; off <<= 1) {
            int cb2 = __shfl_xor(cb, off, 64);
            int mm2 = __shfl_xor(mm, off, 64);
            cb = cb < cb2 ? cb : cb2;
            mm = mm > mm2 ? mm : mm2;
        }
        cutbin = cb;
    }

    if (nw > 0) {
#pragma unroll
        for (int t = 0; t < 16; ++t) {
            const int si = (t * 64 + lane) * 4;
            unsigned ev = *(const unsigned*)&enc[wid][si];
            if (!ev) continue;
#pragma unroll
            for (int i = 0; i < 4; ++i) {
                unsigned e = (ev >> (8 * i)) & 0xFFu;
                int bin = (int)(e & 0x7Fu) - 1;
                if (e && bin > cutbin) {
                    out[rowoff + si + i] = (e & 0x80u) ? -INIT_STRENGTH : INIT_STRENGTH;
                } else if (e && bin == cutbin) {
                    int idx = atomicAdd(&mcnt[wid], 1);
                    if (idx < CAPM) mlist[wid][idx] = (e << 16) | (unsigned)(si + i);
                }
            }
        }
        int L = mcnt[wid]; if (L > CAPM) L = CAPM;
        for (int t0 = 0; t0 < L; t0 += 64) {
            int t = t0 + lane;
            if (t < L) {
                unsigned me = mlist[wid][t];
                int mycol = (int)(me & 0xFFFFu);
                int rk = 0;
                for (int t2 = 0; t2 < L; ++t2)
                    rk += ((int)(mlist[wid][t2] & 0xFFFFu) < mycol) ? 1 : 0;
                if (rk < mm)
                    out[rowoff + mycol] = (me & 0x800000u) ? -INIT_STRENGTH : INIT_STRENGTH;
            }
        }
    }

    if (cpw) {
        int S = scnt[wid]; if (S > CAPS) S = CAPS;
        for (int t = lane; t < S; t += 64) out[rowoff + slist[wid][t]] = 0.f;
    }
}

// ---------------- kernel 3: finalize scalars ----------------
__global__ void final_kernel(const float* __restrict__ acc, float* __restrict__ out) {
    float c = 0.f, p = 0.f, z = 0.f;
    for (int s = 0; s < NSLOT; ++s) {
        c += acc[s * 4 + 0];
        p += acc[s * 4 + 1];
        z += acc[s * 4 + 2];
    }
    out[NN + 0] = c;
    out[NN + 1] = p;
    out[NN + 2] = z * (1.0f / (float)NN);
}

extern "C" void kernel_launch(void* const* d_in, const int* in_sizes, int n_in,
                              void* d_out, int out_size, void* d_ws, size_t ws_size,
                              hipStream_t stream) {
    const float* W   = (const float*)d_in[0];   // weight [4096,4096]
    const float* act = (const float*)d_in[1];   // activations [16,4096]
    float* out = (float*)d_out;                 // [w2 (N*N), created, pruned, sparsity]
    float* norm = (float*)d_ws;                 // [B][N]
    float* acc = norm + (size_t)B * N;          // 64 slots x 4 floats

    const size_t enc_off = (size_t)1 << 20;     // enc at +1 MB (norm/acc/rowcnt fit below)
    const size_t ws_needed = enc_off + (size_t)NN;  // 1 MB + 16 MB

    prep_kernel<<<N / 256, 256, 0, stream>>>(act, norm, acc);
    if (ws_size >= ws_needed) {
        int* rowcnt = (int*)(acc + NSLOT * 4);                  // 4096 x 16 x int2 = 512 KB
        unsigned char* enc = (unsigned char*)d_ws + enc_off;    // 16 MB
        stream_kernel<<<4096, 256, 0, stream>>>(W, norm, out, enc, rowcnt);
        select_kernel<<<N, 256, 0, stream>>>(enc, rowcnt, out, acc);
    } else {
        fused_kernel<<<N / R, 256, 0, stream>>>(W, norm, out, acc);
    }
    final_kernel<<<1, 1, 0, stream>>>(acc, out);
}